// Round 2
// baseline (86.374 us; speedup 1.0000x reference)
//
#include <hip/hip_runtime.h>
#include <math.h>

#define Bq 512
#define Dq 256

__device__ __forceinline__ float waveReduceSum(float v) {
    #pragma unroll
    for (int off = 32; off > 0; off >>= 1)
        v += __shfl_xor(v, off, 64);
    return v;
}

// Kernel 1: per-row L2 norm. Writes transposed fT[k*Bq+i] = a, norms[i], and
// zeroes the completion counter used by pair's last-block finale.
__global__ __launch_bounds__(256) void prep_kernel(
        const float* __restrict__ feat,
        float* __restrict__ fT, float* __restrict__ norms,
        int* __restrict__ counter) {
    int i = blockIdx.x;
    int k = threadIdx.x;
    float x = feat[i * Dq + k];
    float ss = waveReduceSum(x * x);
    __shared__ float wsum[4];
    int wid = threadIdx.x >> 6, lane = threadIdx.x & 63;
    if (lane == 0) wsum[wid] = ss;
    __syncthreads();
    float tot = wsum[0] + wsum[1] + wsum[2] + wsum[3];
    float n = fmaxf(sqrtf(tot), 1e-12f);
    fT[k * Bq + i] = x / n;           // bit-identical a = x/n as before
    if (k == 0) norms[i] = n;
    if (i == 0 && k == 0) *counter = 0;
}

// Kernel 2: block per i, 512 threads (t == j). i-row coefs computed in-kernel
// from feat row i / norms[i] (same op sequence as the old prep => bit-exact).
// k-loop unchanged from round 1 (measured at issue/VALU floor).
// Finale fused: block i computes t_i = S_i/B - log(V_i); the last block to
// finish reduces all t_i with the exact same reduce structure final_kernel used.
__global__ __launch_bounds__(512) void pair_kernel(
        const float* __restrict__ feat,
        const float* __restrict__ fT, const float* __restrict__ norms,
        float* __restrict__ tws, int* __restrict__ counter,
        float* __restrict__ out) {
    const int i = blockIdx.x;
    const int t = threadIdx.x;   // t == j

    __shared__ __align__(16) float s_c1[Dq];
    __shared__ __align__(16) float s_c2[Dq];
    __shared__ __align__(16) float s_a1[Dq];
    __shared__ __align__(16) float s_a2[Dq];
    if (t < Dq) {
        float a  = feat[i * Dq + t] / norms[i];  // same x/n as prep => same bits
        float a2 = a * a;
        float c0 = 1.0f + a2 * a;
        s_a1[t] = a;
        s_a2[t] = a2;
        s_c1[t] = a * c0;
        s_c2[t] = c0 * c0;
    }
    __syncthreads();

    float du = 0.f, nu = 0.f, dv = 0.f, nv = 0.f;
    const float* __restrict__ bp = fT + t;

    #pragma unroll 2
    for (int k0 = 0; k0 < Dq; k0 += 8) {
        float b[8];
        #pragma unroll
        for (int u = 0; u < 8; ++u) b[u] = bp[(k0 + u) * Bq];

        float4 q1a = *(const float4*)(s_c1 + k0), q1b = *(const float4*)(s_c1 + k0 + 4);
        float4 q2a = *(const float4*)(s_c2 + k0), q2b = *(const float4*)(s_c2 + k0 + 4);
        float4 q3a = *(const float4*)(s_a1 + k0), q3b = *(const float4*)(s_a1 + k0 + 4);
        float4 q4a = *(const float4*)(s_a2 + k0), q4b = *(const float4*)(s_a2 + k0 + 4);
        const float c1[8] = {q1a.x, q1a.y, q1a.z, q1a.w, q1b.x, q1b.y, q1b.z, q1b.w};
        const float c2[8] = {q2a.x, q2a.y, q2a.z, q2a.w, q2b.x, q2b.y, q2b.z, q2b.w};
        const float a1[8] = {q3a.x, q3a.y, q3a.z, q3a.w, q3b.x, q3b.y, q3b.z, q3b.w};
        const float a2[8] = {q4a.x, q4a.y, q4a.z, q4a.w, q4b.x, q4b.y, q4b.z, q4b.w};

        #pragma unroll
        for (int u = 0; u < 8; ++u) {
            float b1 = b[u];
            float bb = b1 * b1;
            float w  = fmaf(a2[u], b1, 1.0f);
            float wb = w * b1;
            du = fmaf(c1[u], b1, du);
            nu = fmaf(c2[u], bb, nu);
            dv = fmaf(a1[u], wb, dv);
            nv = fmaf(wb,    wb, nv);
        }
    }

    const float Tinv = 1.0f / 0.07f;
    float raw_s = du / fmaxf(sqrtf(nu), 1e-12f) * Tinv;
    float raw_o = dv / fmaxf(sqrtf(nv), 1e-12f) * Tinv;

    float sS = raw_s;                      // diagonal included in S
    float sV = (t == i) ? 0.f : (expf(raw_s) + 3.0f * expf(raw_o));

    sS = waveReduceSum(sS);
    sV = waveReduceSum(sV);
    __shared__ float redS[8], redV[8];
    int wid = t >> 6, lane = t & 63;
    if (lane == 0) { redS[wid] = sS; redV[wid] = sV; }
    __syncthreads();

    __shared__ int s_last;
    if (t == 0) {
        float S = 0.f, V = 0.f;
        #pragma unroll
        for (int w2 = 0; w2 < 8; ++w2) { S += redS[w2]; V += redV[w2]; }
        float ti = S * (1.0f / Bq) - logf(V);   // same ops as old final_kernel
        __hip_atomic_store(&tws[i], ti, __ATOMIC_RELEASE, __HIP_MEMORY_SCOPE_AGENT);
        int old = __hip_atomic_fetch_add(counter, 1, __ATOMIC_ACQ_REL,
                                         __HIP_MEMORY_SCOPE_AGENT);
        s_last = (old == Bq - 1) ? 1 : 0;
    }
    __syncthreads();

    if (s_last) {
        // exact replica of old final_kernel's reduce => bit-identical loss
        float v = __hip_atomic_load(&tws[t], __ATOMIC_RELAXED,
                                    __HIP_MEMORY_SCOPE_AGENT);
        float r = waveReduceSum(v);
        __shared__ float red[8];
        if (lane == 0) red[wid] = r;
        __syncthreads();
        if (t == 0) {
            float s = 0.f;
            #pragma unroll
            for (int w = 0; w < 8; ++w) s += red[w];
            out[0] = -s / (float)Bq;
        }
    }
}

extern "C" void kernel_launch(void* const* d_in, const int* in_sizes, int n_in,
                              void* d_out, int out_size, void* d_ws, size_t ws_size,
                              hipStream_t stream) {
    const float* feat = (const float*)d_in[0];
    float* ws = (float*)d_ws;
    float* fT    = ws;                // Bq*Dq
    float* norms = fT + Bq * Dq;      // Bq
    float* tws   = norms + Bq;        // Bq
    int*   counter = (int*)(tws + Bq);

    prep_kernel<<<Bq, Dq, 0, stream>>>(feat, fT, norms, counter);
    pair_kernel<<<Bq, 512, 0, stream>>>(feat, fT, norms, tws, counter,
                                        (float*)d_out);
}

// Round 3
// 83.119 us; speedup vs baseline: 1.0392x; 1.0392x over previous
//
#include <hip/hip_runtime.h>
#include <math.h>

#define Bq 512
#define Dq 256

__device__ __forceinline__ float waveReduceSum(float v) {
    #pragma unroll
    for (int off = 32; off > 0; off >>= 1)
        v += __shfl_xor(v, off, 64);
    return v;
}

// Kernel 1: per-row L2 norm. Writes transposed fT[k*Bq+i] = a and norms[i].
__global__ __launch_bounds__(256) void prep_kernel(
        const float* __restrict__ feat,
        float* __restrict__ fT, float* __restrict__ norms) {
    int i = blockIdx.x;
    int k = threadIdx.x;
    float x = feat[i * Dq + k];
    float ss = waveReduceSum(x * x);
    __shared__ float wsum[4];
    int wid = threadIdx.x >> 6, lane = threadIdx.x & 63;
    if (lane == 0) wsum[wid] = ss;
    __syncthreads();
    float tot = wsum[0] + wsum[1] + wsum[2] + wsum[3];
    float n = fmaxf(sqrtf(tot), 1e-12f);
    fT[k * Bq + i] = x / n;           // bit-identical a = x/n
    if (k == 0) norms[i] = n;
}

// Kernel 2: block owns TWO rows {i0, i0+1}; 512 threads, t == j.
// Each fT load b (and bb = b*b) is reused for both i's: halves L2 traffic and
// per-FLOP address math vs round 1. Per-(i,j) fmaf chain over k unchanged
// => bit-identical accumulators. Coefs computed in-LDS from feat/norms with
// the same op sequence as before (a = x/n).
__global__ __launch_bounds__(512) void pair_kernel(
        const float* __restrict__ feat,
        const float* __restrict__ fT, const float* __restrict__ norms,
        float* __restrict__ Sv, float* __restrict__ Vv) {
    const int i0 = blockIdx.x * 2;
    const int t = threadIdx.x;   // t == j

    __shared__ __align__(16) float s_c1[2][Dq];
    __shared__ __align__(16) float s_c2[2][Dq];
    __shared__ __align__(16) float s_a1[2][Dq];
    __shared__ __align__(16) float s_a2[2][Dq];
    {
        int ci = t >> 8;          // 0 for threads 0..255 (row i0), 1 for i0+1
        int ck = t & 255;
        float a  = feat[(i0 + ci) * Dq + ck] / norms[i0 + ci];
        float a2 = a * a;
        float c0 = 1.0f + a2 * a;
        s_a1[ci][ck] = a;
        s_a2[ci][ck] = a2;
        s_c1[ci][ck] = a * c0;
        s_c2[ci][ck] = c0 * c0;
    }
    __syncthreads();

    float du0 = 0.f, nu0 = 0.f, dv0 = 0.f, nv0 = 0.f;
    float du1 = 0.f, nu1 = 0.f, dv1 = 0.f, nv1 = 0.f;
    const float* __restrict__ bp = fT + t;

    for (int k0 = 0; k0 < Dq; k0 += 8) {
        // batch the 8 global loads (shared by both rows)
        float b[8];
        #pragma unroll
        for (int u = 0; u < 8; ++u) b[u] = bp[(k0 + u) * Bq];

        float4 p0a = *(const float4*)(&s_c1[0][k0]), p0b = *(const float4*)(&s_c1[0][k0 + 4]);
        float4 p1a = *(const float4*)(&s_c2[0][k0]), p1b = *(const float4*)(&s_c2[0][k0 + 4]);
        float4 p2a = *(const float4*)(&s_a1[0][k0]), p2b = *(const float4*)(&s_a1[0][k0 + 4]);
        float4 p3a = *(const float4*)(&s_a2[0][k0]), p3b = *(const float4*)(&s_a2[0][k0 + 4]);
        float4 q0a = *(const float4*)(&s_c1[1][k0]), q0b = *(const float4*)(&s_c1[1][k0 + 4]);
        float4 q1a = *(const float4*)(&s_c2[1][k0]), q1b = *(const float4*)(&s_c2[1][k0 + 4]);
        float4 q2a = *(const float4*)(&s_a1[1][k0]), q2b = *(const float4*)(&s_a1[1][k0 + 4]);
        float4 q3a = *(const float4*)(&s_a2[1][k0]), q3b = *(const float4*)(&s_a2[1][k0 + 4]);
        const float c1_0[8] = {p0a.x, p0a.y, p0a.z, p0a.w, p0b.x, p0b.y, p0b.z, p0b.w};
        const float c2_0[8] = {p1a.x, p1a.y, p1a.z, p1a.w, p1b.x, p1b.y, p1b.z, p1b.w};
        const float a1_0[8] = {p2a.x, p2a.y, p2a.z, p2a.w, p2b.x, p2b.y, p2b.z, p2b.w};
        const float a2_0[8] = {p3a.x, p3a.y, p3a.z, p3a.w, p3b.x, p3b.y, p3b.z, p3b.w};
        const float c1_1[8] = {q0a.x, q0a.y, q0a.z, q0a.w, q0b.x, q0b.y, q0b.z, q0b.w};
        const float c2_1[8] = {q1a.x, q1a.y, q1a.z, q1a.w, q1b.x, q1b.y, q1b.z, q1b.w};
        const float a1_1[8] = {q2a.x, q2a.y, q2a.z, q2a.w, q2b.x, q2b.y, q2b.z, q2b.w};
        const float a2_1[8] = {q3a.x, q3a.y, q3a.z, q3a.w, q3b.x, q3b.y, q3b.z, q3b.w};

        #pragma unroll
        for (int u = 0; u < 8; ++u) {
            float b1 = b[u];
            float bb = b1 * b1;
            // row i0
            {
                float w  = fmaf(a2_0[u], b1, 1.0f);
                float wb = w * b1;
                du0 = fmaf(c1_0[u], b1, du0);
                nu0 = fmaf(c2_0[u], bb, nu0);
                dv0 = fmaf(a1_0[u], wb, dv0);
                nv0 = fmaf(wb,      wb, nv0);
            }
            // row i0+1
            {
                float w  = fmaf(a2_1[u], b1, 1.0f);
                float wb = w * b1;
                du1 = fmaf(c1_1[u], b1, du1);
                nu1 = fmaf(c2_1[u], bb, nu1);
                dv1 = fmaf(a1_1[u], wb, dv1);
                nv1 = fmaf(wb,      wb, nv1);
            }
        }
    }

    const float Tinv = 1.0f / 0.07f;
    float raw_s0 = du0 / fmaxf(sqrtf(nu0), 1e-12f) * Tinv;
    float raw_o0 = dv0 / fmaxf(sqrtf(nv0), 1e-12f) * Tinv;
    float raw_s1 = du1 / fmaxf(sqrtf(nu1), 1e-12f) * Tinv;
    float raw_o1 = dv1 / fmaxf(sqrtf(nv1), 1e-12f) * Tinv;

    float sS0 = raw_s0;  // diagonal included in S
    float sV0 = (t == i0)     ? 0.f : (expf(raw_s0) + 3.0f * expf(raw_o0));
    float sS1 = raw_s1;
    float sV1 = (t == i0 + 1) ? 0.f : (expf(raw_s1) + 3.0f * expf(raw_o1));

    sS0 = waveReduceSum(sS0);
    sV0 = waveReduceSum(sV0);
    sS1 = waveReduceSum(sS1);
    sV1 = waveReduceSum(sV1);
    __shared__ float redS[2][8], redV[2][8];
    int wid = t >> 6, lane = t & 63;
    if (lane == 0) {
        redS[0][wid] = sS0; redV[0][wid] = sV0;
        redS[1][wid] = sS1; redV[1][wid] = sV1;
    }
    __syncthreads();
    if (t == 0) {
        float S0 = 0.f, V0 = 0.f, S1 = 0.f, V1 = 0.f;
        #pragma unroll
        for (int w2 = 0; w2 < 8; ++w2) {
            S0 += redS[0][w2]; V0 += redV[0][w2];
            S1 += redS[1][w2]; V1 += redV[1][w2];
        }
        Sv[i0] = S0;     Vv[i0] = V0;
        Sv[i0 + 1] = S1; Vv[i0 + 1] = V1;
    }
}

// Kernel 3: loss = -(1/B) * sum_i ( S[i]/B - log(V[i]) )
__global__ __launch_bounds__(512) void final_kernel(
        const float* __restrict__ Sv, const float* __restrict__ Vv,
        float* __restrict__ out) {
    int i = threadIdx.x;
    float t = Sv[i] * (1.0f / Bq) - logf(Vv[i]);
    t = waveReduceSum(t);
    __shared__ float red[8];
    int wid = i >> 6, lane = i & 63;
    if (lane == 0) red[wid] = t;
    __syncthreads();
    if (i == 0) {
        float s = 0.f;
        #pragma unroll
        for (int w = 0; w < 8; ++w) s += red[w];
        out[0] = -s / (float)Bq;
    }
}

extern "C" void kernel_launch(void* const* d_in, const int* in_sizes, int n_in,
                              void* d_out, int out_size, void* d_ws, size_t ws_size,
                              hipStream_t stream) {
    const float* feat = (const float*)d_in[0];
    float* ws = (float*)d_ws;
    float* fT    = ws;                // Bq*Dq
    float* norms = fT + Bq * Dq;      // Bq
    float* Sv    = norms + Bq;        // Bq
    float* Vv    = Sv + Bq;           // Bq

    prep_kernel<<<Bq, Dq, 0, stream>>>(feat, fT, norms);
    pair_kernel<<<Bq / 2, 512, 0, stream>>>(feat, fT, norms, Sv, Vv);
    final_kernel<<<1, Bq, 0, stream>>>(Sv, Vv, (float*)d_out);
}

// Round 4
// 79.838 us; speedup vs baseline: 1.0819x; 1.0411x over previous
//
#include <hip/hip_runtime.h>
#include <math.h>

#define Bq 512
#define Dq 256

__device__ __forceinline__ float waveReduceSum(float v) {
    #pragma unroll
    for (int off = 32; off > 0; off >>= 1)
        v += __shfl_xor(v, off, 64);
    return v;
}

// Kernel 1: per-row L2 norm. Writes transposed fT[k*Bq+i] = a, norms[i], and
// zeroes the completion counter (visible to pair via end-of-dispatch flush).
__global__ __launch_bounds__(256) void prep_kernel(
        const float* __restrict__ feat,
        float* __restrict__ fT, float* __restrict__ norms,
        int* __restrict__ counter) {
    int i = blockIdx.x;
    int k = threadIdx.x;
    float x = feat[i * Dq + k];
    float ss = waveReduceSum(x * x);
    __shared__ float wsum[4];
    int wid = threadIdx.x >> 6, lane = threadIdx.x & 63;
    if (lane == 0) wsum[wid] = ss;
    __syncthreads();
    float tot = wsum[0] + wsum[1] + wsum[2] + wsum[3];
    float n = fmaxf(sqrtf(tot), 1e-12f);
    fT[k * Bq + i] = x / n;           // bit-identical a = x/n
    if (k == 0) norms[i] = n;
    if (i == 0 && k == 0) *counter = 0;
}

// Kernel 2: block per i (512 threads, t == j), R1 structure + two changes:
//  (a) k-loop software-pipelined: b-loads for chunk k+8 issued while chunk k's
//      FMAs run (double-buffered regs; k-order of accumulation unchanged).
//  (b) finale fused via cheap last-block pattern: relaxed agent atomics only,
//      ordering by s_waitcnt vmcnt(0) in thread 0 — NO release fences (the
//      R2 regression was the per-block buffer_wbl2 storm from ACQ_REL/RELEASE).
__global__ __launch_bounds__(512) void pair_kernel(
        const float* __restrict__ feat,
        const float* __restrict__ fT, const float* __restrict__ norms,
        float* __restrict__ tws, int* __restrict__ counter,
        float* __restrict__ out) {
    const int i = blockIdx.x;
    const int t = threadIdx.x;   // t == j

    __shared__ __align__(16) float s_c1[Dq];
    __shared__ __align__(16) float s_c2[Dq];
    __shared__ __align__(16) float s_a1[Dq];
    __shared__ __align__(16) float s_a2[Dq];
    if (t < Dq) {
        float a  = feat[i * Dq + t] / norms[i];  // same x/n as prep => same bits
        float a2 = a * a;
        float c0 = 1.0f + a2 * a;
        s_a1[t] = a;
        s_a2[t] = a2;
        s_c1[t] = a * c0;
        s_c2[t] = c0 * c0;
    }
    __syncthreads();

    float du = 0.f, nu = 0.f, dv = 0.f, nv = 0.f;
    const float* __restrict__ bp = fT + t;

    float bA[8], bB[8];
    #pragma unroll
    for (int u = 0; u < 8; ++u) bA[u] = bp[u * Bq];   // prologue: chunk 0

    #define PROCESS(BREG, K0)                                                  \
    do {                                                                       \
        float4 q1a = *(const float4*)(s_c1 + (K0)), q1b = *(const float4*)(s_c1 + (K0) + 4); \
        float4 q2a = *(const float4*)(s_c2 + (K0)), q2b = *(const float4*)(s_c2 + (K0) + 4); \
        float4 q3a = *(const float4*)(s_a1 + (K0)), q3b = *(const float4*)(s_a1 + (K0) + 4); \
        float4 q4a = *(const float4*)(s_a2 + (K0)), q4b = *(const float4*)(s_a2 + (K0) + 4); \
        const float c1[8] = {q1a.x, q1a.y, q1a.z, q1a.w, q1b.x, q1b.y, q1b.z, q1b.w}; \
        const float c2[8] = {q2a.x, q2a.y, q2a.z, q2a.w, q2b.x, q2b.y, q2b.z, q2b.w}; \
        const float a1[8] = {q3a.x, q3a.y, q3a.z, q3a.w, q3b.x, q3b.y, q3b.z, q3b.w}; \
        const float a2[8] = {q4a.x, q4a.y, q4a.z, q4a.w, q4b.x, q4b.y, q4b.z, q4b.w}; \
        _Pragma("unroll")                                                      \
        for (int u = 0; u < 8; ++u) {                                          \
            float b1 = (BREG)[u];                                              \
            float bb = b1 * b1;                                                \
            float w  = fmaf(a2[u], b1, 1.0f);                                  \
            float wb = w * b1;                                                 \
            du = fmaf(c1[u], b1, du);                                          \
            nu = fmaf(c2[u], bb, nu);                                          \
            dv = fmaf(a1[u], wb, dv);                                          \
            nv = fmaf(wb,    wb, nv);                                          \
        }                                                                      \
    } while (0)

    for (int k0 = 0; k0 < Dq; k0 += 16) {
        // prefetch chunk k0+8 while processing chunk k0
        #pragma unroll
        for (int u = 0; u < 8; ++u) bB[u] = bp[(k0 + 8 + u) * Bq];
        PROCESS(bA, k0);
        // prefetch chunk k0+16 while processing chunk k0+8 (skip on last iter)
        if (k0 + 16 < Dq) {
            #pragma unroll
            for (int u = 0; u < 8; ++u) bA[u] = bp[(k0 + 16 + u) * Bq];
        }
        PROCESS(bB, k0 + 8);
    }
    #undef PROCESS

    const float Tinv = 1.0f / 0.07f;
    float raw_s = du / fmaxf(sqrtf(nu), 1e-12f) * Tinv;
    float raw_o = dv / fmaxf(sqrtf(nv), 1e-12f) * Tinv;

    float sS = raw_s;                      // diagonal included in S
    float sV = (t == i) ? 0.f : (expf(raw_s) + 3.0f * expf(raw_o));

    sS = waveReduceSum(sS);
    sV = waveReduceSum(sV);
    __shared__ float redS[8], redV[8];
    int wid = t >> 6, lane = t & 63;
    if (lane == 0) { redS[wid] = sS; redV[wid] = sV; }
    __syncthreads();

    __shared__ int s_last;
    if (t == 0) {
        float S = 0.f, V = 0.f;
        #pragma unroll
        for (int w2 = 0; w2 < 8; ++w2) { S += redS[w2]; V += redV[w2]; }
        float ti = S * (1.0f / Bq) - logf(V);   // same ops as old final_kernel
        // relaxed agent store (write-through to device-coherent point, no fence)
        __hip_atomic_store(&tws[i], ti, __ATOMIC_RELAXED, __HIP_MEMORY_SCOPE_AGENT);
        // order: store must COMPLETE before the counter bump is visible.
        asm volatile("s_waitcnt vmcnt(0)" ::: "memory");
        int old = __hip_atomic_fetch_add(counter, 1, __ATOMIC_RELAXED,
                                         __HIP_MEMORY_SCOPE_AGENT);
        s_last = (old == Bq - 1) ? 1 : 0;
    }
    __syncthreads();

    if (s_last) {
        // exact replica of old final_kernel's reduce => bit-identical loss
        float v = __hip_atomic_load(&tws[t], __ATOMIC_RELAXED,
                                    __HIP_MEMORY_SCOPE_AGENT);
        float r = waveReduceSum(v);
        __shared__ float red[8];
        if (lane == 0) red[wid] = r;
        __syncthreads();
        if (t == 0) {
            float s = 0.f;
            #pragma unroll
            for (int w = 0; w < 8; ++w) s += red[w];
            out[0] = -s / (float)Bq;
        }
    }
}

extern "C" void kernel_launch(void* const* d_in, const int* in_sizes, int n_in,
                              void* d_out, int out_size, void* d_ws, size_t ws_size,
                              hipStream_t stream) {
    const float* feat = (const float*)d_in[0];
    float* ws = (float*)d_ws;
    float* fT    = ws;                // Bq*Dq
    float* norms = fT + Bq * Dq;      // Bq
    float* tws   = norms + Bq;        // Bq
    int*   counter = (int*)(tws + Bq);

    prep_kernel<<<Bq, Dq, 0, stream>>>(feat, fT, norms, counter);
    pair_kernel<<<Bq, 512, 0, stream>>>(feat, fT, norms, tws, counter,
                                        (float*)d_out);
}

// Round 5
// 74.300 us; speedup vs baseline: 1.1625x; 1.0745x over previous
//
#include <hip/hip_runtime.h>
#include <math.h>

#define Bq 512
#define Dq 256

typedef float v2f __attribute__((ext_vector_type(2)));

__device__ __forceinline__ float waveReduceSum(float v) {
    #pragma unroll
    for (int off = 32; off > 0; off >>= 1)
        v += __shfl_xor(v, off, 64);
    return v;
}

// Kernel 1: per-row L2 norm. Writes transposed fT[k*Bq+i] = a and norms[i].
__global__ __launch_bounds__(256) void prep_kernel(
        const float* __restrict__ feat,
        float* __restrict__ fT, float* __restrict__ norms) {
    int i = blockIdx.x;
    int k = threadIdx.x;
    float x = feat[i * Dq + k];
    float ss = waveReduceSum(x * x);
    __shared__ float wsum[4];
    int wid = threadIdx.x >> 6, lane = threadIdx.x & 63;
    if (lane == 0) wsum[wid] = ss;
    __syncthreads();
    float tot = wsum[0] + wsum[1] + wsum[2] + wsum[3];
    float n = fmaxf(sqrtf(tot), 1e-12f);
    fT[k * Bq + i] = x / n;           // bit-identical a = x/n
    if (k == 0) norms[i] = n;
}

// Kernel 2: block per i, 256 threads, thread t owns j0=2t and j0+1 PACKED as
// float2 (v_pk_fma_f32 / v_pk_mul_f32): same FLOPs as R0's scalar 2-j chain in
// half the VALU issue slots. Per-component op order identical to the scalar
// version => bit-identical results. fT read as one coalesced dwordx2 per k.
__global__ __launch_bounds__(256) void pair_kernel(
        const float* __restrict__ feat,
        const float* __restrict__ fT, const float* __restrict__ norms,
        float* __restrict__ Sv, float* __restrict__ Vv) {
    const int i = blockIdx.x;
    const int t = threadIdx.x;
    const int j0 = 2 * t;

    __shared__ __align__(16) float s_c1[Dq];
    __shared__ __align__(16) float s_c2[Dq];
    __shared__ __align__(16) float s_a1[Dq];
    __shared__ __align__(16) float s_a2[Dq];
    {
        float a  = feat[i * Dq + t] / norms[i];  // same x/n as prep => same bits
        float a2 = a * a;
        float c0 = 1.0f + a2 * a;
        s_a1[t] = a;
        s_a2[t] = a2;
        s_c1[t] = a * c0;
        s_c2[t] = c0 * c0;
    }
    __syncthreads();

    v2f du = {0.f, 0.f}, nu = {0.f, 0.f}, dv = {0.f, 0.f}, nv = {0.f, 0.f};
    const float* __restrict__ bp = fT + j0;
    const v2f one2 = {1.0f, 1.0f};

    for (int k0 = 0; k0 < Dq; k0 += 8) {
        // batch the 8 packed loads (8B/lane, coalesced 2KB/wave)
        v2f b[8];
        #pragma unroll
        for (int u = 0; u < 8; ++u)
            b[u] = *(const v2f*)(bp + (k0 + u) * Bq);

        float4 q1a = *(const float4*)(s_c1 + k0), q1b = *(const float4*)(s_c1 + k0 + 4);
        float4 q2a = *(const float4*)(s_c2 + k0), q2b = *(const float4*)(s_c2 + k0 + 4);
        float4 q3a = *(const float4*)(s_a1 + k0), q3b = *(const float4*)(s_a1 + k0 + 4);
        float4 q4a = *(const float4*)(s_a2 + k0), q4b = *(const float4*)(s_a2 + k0 + 4);
        const float c1a[8] = {q1a.x, q1a.y, q1a.z, q1a.w, q1b.x, q1b.y, q1b.z, q1b.w};
        const float c2a[8] = {q2a.x, q2a.y, q2a.z, q2a.w, q2b.x, q2b.y, q2b.z, q2b.w};
        const float a1a[8] = {q3a.x, q3a.y, q3a.z, q3a.w, q3b.x, q3b.y, q3b.z, q3b.w};
        const float a2a[8] = {q4a.x, q4a.y, q4a.z, q4a.w, q4b.x, q4b.y, q4b.z, q4b.w};

        #pragma unroll
        for (int u = 0; u < 8; ++u) {
            v2f bv = b[u];
            v2f bb = bv * bv;
            v2f a2s = {a2a[u], a2a[u]};
            v2f w   = __builtin_elementwise_fma(a2s, bv, one2);
            v2f wb  = w * bv;
            v2f c1s = {c1a[u], c1a[u]};
            v2f c2s = {c2a[u], c2a[u]};
            v2f a1s = {a1a[u], a1a[u]};
            du = __builtin_elementwise_fma(c1s, bv, du);
            nu = __builtin_elementwise_fma(c2s, bb, nu);
            dv = __builtin_elementwise_fma(a1s, wb, dv);
            nv = __builtin_elementwise_fma(wb,  wb, nv);
        }
    }

    const float Tinv = 1.0f / 0.07f;
    float raw_s0 = du.x / fmaxf(sqrtf(nu.x), 1e-12f) * Tinv;
    float raw_o0 = dv.x / fmaxf(sqrtf(nv.x), 1e-12f) * Tinv;
    float raw_s1 = du.y / fmaxf(sqrtf(nu.y), 1e-12f) * Tinv;
    float raw_o1 = dv.y / fmaxf(sqrtf(nv.y), 1e-12f) * Tinv;

    float sS = raw_s0 + raw_s1;   // diagonal included in S
    float sV = 0.f;
    if (j0 != i)     sV += expf(raw_s0) + 3.0f * expf(raw_o0);
    if (j0 + 1 != i) sV += expf(raw_s1) + 3.0f * expf(raw_o1);

    sS = waveReduceSum(sS);
    sV = waveReduceSum(sV);
    __shared__ float redS[4], redV[4];
    int wid = t >> 6, lane = t & 63;
    if (lane == 0) { redS[wid] = sS; redV[wid] = sV; }
    __syncthreads();
    if (t == 0) {
        float S = 0.f, V = 0.f;
        #pragma unroll
        for (int w2 = 0; w2 < 4; ++w2) { S += redS[w2]; V += redV[w2]; }
        Sv[i] = S;
        Vv[i] = V;
    }
}

// Kernel 3: loss = -(1/B) * sum_i ( S[i]/B - log(V[i]) )
__global__ __launch_bounds__(512) void final_kernel(
        const float* __restrict__ Sv, const float* __restrict__ Vv,
        float* __restrict__ out) {
    int i = threadIdx.x;
    float t = Sv[i] * (1.0f / Bq) - logf(Vv[i]);
    t = waveReduceSum(t);
    __shared__ float red[8];
    int wid = i >> 6, lane = i & 63;
    if (lane == 0) red[wid] = t;
    __syncthreads();
    if (i == 0) {
        float s = 0.f;
        #pragma unroll
        for (int w = 0; w < 8; ++w) s += red[w];
        out[0] = -s / (float)Bq;
    }
}

extern "C" void kernel_launch(void* const* d_in, const int* in_sizes, int n_in,
                              void* d_out, int out_size, void* d_ws, size_t ws_size,
                              hipStream_t stream) {
    const float* feat = (const float*)d_in[0];
    float* ws = (float*)d_ws;
    float* fT    = ws;                // Bq*Dq
    float* norms = fT + Bq * Dq;      // Bq
    float* Sv    = norms + Bq;        // Bq
    float* Vv    = Sv + Bq;           // Bq

    prep_kernel<<<Bq, Dq, 0, stream>>>(feat, fT, norms);
    pair_kernel<<<Bq, 256, 0, stream>>>(feat, fT, norms, Sv, Vv);
    final_kernel<<<1, Bq, 0, stream>>>(Sv, Vv, (float*)d_out);
}